// Round 1
// baseline (1245.840 us; speedup 1.0000x reference)
//
#include <hip/hip_runtime.h>
#include <hip/hip_bf16.h>
#include <math.h>

// Problem constants
#define B_     4
#define T_     4096
#define H_     8
#define LD_    128
#define FFN_   512
#define D_     1024
#define TED_   2048
#define TWO_D_ 2048
#define NTOK_  (B_ * T_)      // 16384
#define LN_EPS_ 1e-5f

__device__ __forceinline__ float siluf(float v) { return v / (1.0f + expf(-v)); }
__device__ __forceinline__ float geluf(float v) {
  // exact (erf-based) GELU, matching approximate=False
  return 0.5f * v * (1.0f + erff(v * 0.70710678118654752440f));
}
__device__ __forceinline__ unsigned short f2bf(float v) {  // RNE float->bf16 bits
  unsigned int u = __float_as_uint(v);
  u += 0x7fffu + ((u >> 16) & 1u);
  return (unsigned short)(u >> 16);
}
__device__ __forceinline__ float bflo(unsigned int u) { return __uint_as_float(u << 16); }
__device__ __forceinline__ float bfhi(unsigned int u) { return __uint_as_float(u & 0xffff0000u); }

// ---------------------------------------------------------------------------
// k0: emb_out[b][j] = silu(emb[b]) @ emb_W[:, j] + emb_b[j]
// grid (2048/256=8 col-blocks, 16 k-slices of 128), block 256. fp32 atomics.
// ---------------------------------------------------------------------------
__global__ __launch_bounds__(256) void k0_emb(
    const float* __restrict__ emb, const float* __restrict__ emb_W,
    const float* __restrict__ emb_b, float* __restrict__ emb_out) {
  __shared__ float se[B_][128];
  const int tid = threadIdx.x;
  const int j   = blockIdx.x * 256 + tid;   // output column 0..2047
  const int k0  = blockIdx.y * 128;         // k-slice
  for (int i = tid; i < B_ * 128; i += 256) {
    const int b = i >> 7, k = i & 127;
    se[b][k] = siluf(emb[b * TED_ + k0 + k]);
  }
  __syncthreads();
  float a0 = 0.f, a1 = 0.f, a2 = 0.f, a3 = 0.f;
  const float* Wp = emb_W + (size_t)k0 * TWO_D_ + j;
  for (int k = 0; k < 128; ++k) {
    const float w = Wp[(size_t)k * TWO_D_];  // coalesced across j
    a0 += se[0][k] * w; a1 += se[1][k] * w;
    a2 += se[2][k] * w; a3 += se[3][k] * w;
  }
  if (blockIdx.y == 0) {
    const float bb = emb_b[j];
    a0 += bb; a1 += bb; a2 += bb; a3 += bb;
  }
  atomicAdd(&emb_out[0 * TWO_D_ + j], a0);
  atomicAdd(&emb_out[1 * TWO_D_ + j], a1);
  atomicAdd(&emb_out[2 * TWO_D_ + j], a2);
  atomicAdd(&emb_out[3 * TWO_D_ + j], a3);
}

// ---------------------------------------------------------------------------
// k1: per-head MLP. y[m][h*128+d] = (gelu(x_h[m] @ W1[h] + b1[h]) @ W2[h]) + b2[h]
// grid (16384/32=512 M-blocks, 8 heads), block 256.
// LDS: xs 32x129 fp32 (pad dodges bank conflicts), h1s 32x514 bf16-bits.
// ---------------------------------------------------------------------------
__global__ __launch_bounds__(256) void k1_mlp(
    const float* __restrict__ x, const float* __restrict__ W1,
    const float* __restrict__ b1, const float* __restrict__ W2,
    const float* __restrict__ b2, float* __restrict__ y) {
  __shared__ float xs[32][129];
  __shared__ unsigned short h1s[32][514];
  const int h   = blockIdx.y;
  const int m0  = blockIdx.x * 32;
  const int tid = threadIdx.x;
  const int tl  = tid & 31;   // column-tile lane
  const int tm  = tid >> 5;   // row group: rows tm*4 .. tm*4+3

  // stage x tile (32 tokens x 128 head-cols), float4 coalesced
  {
    const float* xp = x + (size_t)m0 * D_ + h * LD_;
    for (int i = tid; i < 32 * 32; i += 256) {
      const int m = i >> 5, c = (i & 31) * 4;
      const float4 v = *reinterpret_cast<const float4*>(xp + (size_t)m * D_ + c);
      xs[m][c] = v.x; xs[m][c + 1] = v.y; xs[m][c + 2] = v.z; xs[m][c + 3] = v.w;
    }
  }
  __syncthreads();

  // GEMM1 (K=128) + bias + GELU -> h1s (bf16). Thread tile: 4m x 16f (contiguous f).
  {
    float acc[4][16];
    #pragma unroll
    for (int i = 0; i < 4; ++i)
      #pragma unroll
      for (int q = 0; q < 16; ++q) acc[i][q] = 0.f;
    const float* W1p = W1 + (size_t)h * LD_ * FFN_ + tl * 16;
    for (int k = 0; k < 128; ++k) {
      const float xv0 = xs[tm * 4 + 0][k];
      const float xv1 = xs[tm * 4 + 1][k];
      const float xv2 = xs[tm * 4 + 2][k];
      const float xv3 = xs[tm * 4 + 3][k];
      const float* wr = W1p + (size_t)k * FFN_;
      #pragma unroll
      for (int q = 0; q < 4; ++q) {
        const float4 w = *reinterpret_cast<const float4*>(wr + q * 4);
        acc[0][q*4+0] += xv0 * w.x; acc[0][q*4+1] += xv0 * w.y;
        acc[0][q*4+2] += xv0 * w.z; acc[0][q*4+3] += xv0 * w.w;
        acc[1][q*4+0] += xv1 * w.x; acc[1][q*4+1] += xv1 * w.y;
        acc[1][q*4+2] += xv1 * w.z; acc[1][q*4+3] += xv1 * w.w;
        acc[2][q*4+0] += xv2 * w.x; acc[2][q*4+1] += xv2 * w.y;
        acc[2][q*4+2] += xv2 * w.z; acc[2][q*4+3] += xv2 * w.w;
        acc[3][q*4+0] += xv3 * w.x; acc[3][q*4+1] += xv3 * w.y;
        acc[3][q*4+2] += xv3 * w.z; acc[3][q*4+3] += xv3 * w.w;
      }
    }
    const float* b1p = b1 + h * FFN_ + tl * 16;
    #pragma unroll
    for (int i = 0; i < 4; ++i)
      #pragma unroll
      for (int q = 0; q < 16; ++q) {
        const float v = geluf(acc[i][q] + b1p[q]);
        h1s[tm * 4 + i][tl * 16 + q] = f2bf(v);
      }
  }
  __syncthreads();

  // GEMM2 (K=512) + bias -> y. Thread tile: 4m x 4d (contiguous d), k unrolled by 2.
  {
    float acc[4][4];
    #pragma unroll
    for (int i = 0; i < 4; ++i)
      #pragma unroll
      for (int q = 0; q < 4; ++q) acc[i][q] = 0.f;
    const float* W2p = W2 + (size_t)h * FFN_ * LD_ + tl * 4;
    for (int k = 0; k < 512; k += 2) {
      const unsigned int u0 = *reinterpret_cast<const unsigned int*>(&h1s[tm*4+0][k]);
      const unsigned int u1 = *reinterpret_cast<const unsigned int*>(&h1s[tm*4+1][k]);
      const unsigned int u2 = *reinterpret_cast<const unsigned int*>(&h1s[tm*4+2][k]);
      const unsigned int u3 = *reinterpret_cast<const unsigned int*>(&h1s[tm*4+3][k]);
      const float4 wA = *reinterpret_cast<const float4*>(W2p + (size_t)k * LD_);
      const float4 wB = *reinterpret_cast<const float4*>(W2p + (size_t)(k + 1) * LD_);
      const float hA[4] = {bflo(u0), bflo(u1), bflo(u2), bflo(u3)};
      const float hB[4] = {bfhi(u0), bfhi(u1), bfhi(u2), bfhi(u3)};
      #pragma unroll
      for (int i = 0; i < 4; ++i) {
        acc[i][0] += hA[i] * wA.x; acc[i][1] += hA[i] * wA.y;
        acc[i][2] += hA[i] * wA.z; acc[i][3] += hA[i] * wA.w;
        acc[i][0] += hB[i] * wB.x; acc[i][1] += hB[i] * wB.y;
        acc[i][2] += hB[i] * wB.z; acc[i][3] += hB[i] * wB.w;
      }
    }
    const float4 bv = *reinterpret_cast<const float4*>(b2 + h * LD_ + tl * 4);
    #pragma unroll
    for (int i = 0; i < 4; ++i) {
      float4 o;
      o.x = acc[i][0] + bv.x; o.y = acc[i][1] + bv.y;
      o.z = acc[i][2] + bv.z; o.w = acc[i][3] + bv.w;
      *reinterpret_cast<float4*>(
          y + (size_t)(m0 + tm * 4 + i) * D_ + h * LD_ + tl * 4) = o;
    }
  }
}

// ---------------------------------------------------------------------------
// k2: LayerNorm + (1+scale)/shift modulate + SiLU, in place on y.
// grid NTOK_ blocks (one token each), block 256 (4 elems/thread).
// ---------------------------------------------------------------------------
__global__ __launch_bounds__(256) void k2_ln(
    float* __restrict__ y, const float* __restrict__ ln_w,
    const float* __restrict__ ln_b, const float* __restrict__ emb_out) {
  __shared__ float red[8];
  const int bt  = blockIdx.x;
  const int b   = bt >> 12;           // bt = b*T + t, T=4096
  const int tid = threadIdx.x;
  const int d   = tid * 4;
  float4 v = *reinterpret_cast<const float4*>(y + (size_t)bt * D_ + d);
  float s  = v.x + v.y + v.z + v.w;
  float s2 = v.x*v.x + v.y*v.y + v.z*v.z + v.w*v.w;
  #pragma unroll
  for (int off = 32; off > 0; off >>= 1) {
    s  += __shfl_down(s, off);
    s2 += __shfl_down(s2, off);
  }
  if ((tid & 63) == 0) { red[tid >> 6] = s; red[4 + (tid >> 6)] = s2; }
  __syncthreads();
  const float S  = red[0] + red[1] + red[2] + red[3];
  const float S2 = red[4] + red[5] + red[6] + red[7];
  const float mu   = S * (1.0f / D_);
  const float rstd = rsqrtf(S2 * (1.0f / D_) - mu * mu + LN_EPS_);
  const float4 lw = *reinterpret_cast<const float4*>(ln_w + d);
  const float4 lb = *reinterpret_cast<const float4*>(ln_b + d);
  const float4 sc = *reinterpret_cast<const float4*>(emb_out + (size_t)b * TWO_D_ + d);
  const float4 sh = *reinterpret_cast<const float4*>(emb_out + (size_t)b * TWO_D_ + D_ + d);
  v.x = siluf(((v.x - mu) * rstd * lw.x + lb.x) * (1.0f + sc.x) + sh.x);
  v.y = siluf(((v.y - mu) * rstd * lw.y + lb.y) * (1.0f + sc.y) + sh.y);
  v.z = siluf(((v.z - mu) * rstd * lw.z + lb.z) * (1.0f + sc.z) + sh.z);
  v.w = siluf(((v.w - mu) * rstd * lw.w + lb.w) * (1.0f + sc.w) + sh.w);
  *reinterpret_cast<float4*>(y + (size_t)bt * D_ + d) = v;
}

// ---------------------------------------------------------------------------
// k3: out = x + (h @ out_W + out_b). grid (16384/64=256, 1024/128=8), block 256.
// 64x128 output tile; h chunk (64x128) staged in LDS; thread tile 8m x 4n.
// ---------------------------------------------------------------------------
__global__ __launch_bounds__(256) void k3_out(
    const float* __restrict__ hbuf, const float* __restrict__ out_W,
    const float* __restrict__ out_b, const float* __restrict__ x,
    float* __restrict__ out) {
  __shared__ float hs[64][129];
  const int m0  = blockIdx.x * 64;
  const int n0  = blockIdx.y * 128;
  const int tid = threadIdx.x;
  const int tn  = tid & 31;   // n = n0 + tn*4 .. +3
  const int tm  = tid >> 5;   // m = tm*8 .. +7
  float acc[8][4];
  #pragma unroll
  for (int i = 0; i < 8; ++i)
    #pragma unroll
    for (int q = 0; q < 4; ++q) acc[i][q] = 0.f;
  for (int kc = 0; kc < 8; ++kc) {
    for (int i = tid; i < 64 * 32; i += 256) {
      const int m = i >> 5, c = (i & 31) * 4;
      const float4 v = *reinterpret_cast<const float4*>(
          hbuf + (size_t)(m0 + m) * D_ + kc * 128 + c);
      hs[m][c] = v.x; hs[m][c+1] = v.y; hs[m][c+2] = v.z; hs[m][c+3] = v.w;
    }
    __syncthreads();
    const float* Wp = out_W + (size_t)(kc * 128) * D_ + n0 + tn * 4;
    for (int k = 0; k < 128; ++k) {
      const float4 w = *reinterpret_cast<const float4*>(Wp + (size_t)k * D_);
      #pragma unroll
      for (int i = 0; i < 8; ++i) {
        const float hv = hs[tm * 8 + i][k];
        acc[i][0] += hv * w.x; acc[i][1] += hv * w.y;
        acc[i][2] += hv * w.z; acc[i][3] += hv * w.w;
      }
    }
    __syncthreads();  // protect next iteration's hs writes
  }
  const int n = n0 + tn * 4;
  const float4 bv = *reinterpret_cast<const float4*>(out_b + n);
  #pragma unroll
  for (int i = 0; i < 8; ++i) {
    const int m = m0 + tm * 8 + i;
    const float4 xv = *reinterpret_cast<const float4*>(x + (size_t)m * D_ + n);
    float4 o;
    o.x = acc[i][0] + bv.x + xv.x;
    o.y = acc[i][1] + bv.y + xv.y;
    o.z = acc[i][2] + bv.z + xv.z;
    o.w = acc[i][3] + bv.w + xv.w;
    *reinterpret_cast<float4*>(out + (size_t)m * D_ + n) = o;
  }
}

// ---------------------------------------------------------------------------
extern "C" void kernel_launch(void* const* d_in, const int* in_sizes, int n_in,
                              void* d_out, int out_size, void* d_ws, size_t ws_size,
                              hipStream_t stream) {
  const float* x     = (const float*)d_in[0];
  const float* emb   = (const float*)d_in[1];
  const float* W1    = (const float*)d_in[2];
  const float* b1    = (const float*)d_in[3];
  const float* W2    = (const float*)d_in[4];
  const float* b2    = (const float*)d_in[5];
  const float* ln_w  = (const float*)d_in[6];
  const float* ln_b  = (const float*)d_in[7];
  const float* emb_W = (const float*)d_in[8];
  const float* emb_b = (const float*)d_in[9];
  const float* out_W = (const float*)d_in[10];
  const float* out_b = (const float*)d_in[11];
  float* out = (float*)d_out;

  // ws layout: [0, 32KB) emb_out (B x 2D fp32); [1MB, 1MB+64MB) y/h buffer
  float* emb_out = (float*)d_ws;
  float* ybuf    = (float*)((char*)d_ws + (1 << 20));

  hipMemsetAsync(emb_out, 0, B_ * TWO_D_ * sizeof(float), stream);
  k0_emb<<<dim3(TWO_D_ / 256, 16), 256, 0, stream>>>(emb, emb_W, emb_b, emb_out);
  k1_mlp<<<dim3(NTOK_ / 32, H_), 256, 0, stream>>>(x, W1, b1, W2, b2, ybuf);
  k2_ln<<<NTOK_, 256, 0, stream>>>(ybuf, ln_w, ln_b, emb_out);
  k3_out<<<dim3(NTOK_ / 64, D_ / 128), 256, 0, stream>>>(ybuf, out_W, out_b, x, out);
}

// Round 2
// 631.306 us; speedup vs baseline: 1.9734x; 1.9734x over previous
//
#include <hip/hip_runtime.h>
#include <hip/hip_bf16.h>
#include <math.h>

// Problem constants
#define B_     4
#define T_     4096
#define H_     8
#define LD_    128
#define FFN_   512
#define D_     1024
#define TED_   2048
#define TWO_D_ 2048
#define NTOK_  (B_ * T_)      // 16384
#define LN_EPS_ 1e-5f

// ws layout (bytes)
#define WS_EMB_OFF   0                          // 32 KB   (B x 2D fp32)
#define WS_IMG1_OFF  (64 * 1024)                // 1 MB    bf16 wT1 [h][n=512][k=128]
#define WS_IMG2_OFF  (64 * 1024 + 1024 * 1024)  // 1 MB    bf16 wT2 [h][n=128][k=512]
#define WS_Y_OFF     0x230000                   // 64 MB   y fp32 (16384 x 1024)

typedef short bf16x8 __attribute__((ext_vector_type(8)));
typedef float f32x4  __attribute__((ext_vector_type(4)));

__device__ __forceinline__ float siluf(float v) { return v / (1.0f + expf(-v)); }
__device__ __forceinline__ float geluf(float v) {
  // exact (erf-based) GELU, matching approximate=False
  return 0.5f * v * (1.0f + erff(v * 0.70710678118654752440f));
}
__device__ __forceinline__ unsigned short f2bf(float v) {  // RNE float->bf16 bits
  unsigned int u = __float_as_uint(v);
  u += 0x7fffu + ((u >> 16) & 1u);
  return (unsigned short)(u >> 16);
}

// ---------------------------------------------------------------------------
// k0: emb_out[b][j] = silu(emb[b]) @ emb_W[:, j] + emb_b[j]
// ---------------------------------------------------------------------------
__global__ __launch_bounds__(256) void k0_emb(
    const float* __restrict__ emb, const float* __restrict__ emb_W,
    const float* __restrict__ emb_b, float* __restrict__ emb_out) {
  __shared__ float se[B_][128];
  const int tid = threadIdx.x;
  const int j   = blockIdx.x * 256 + tid;
  const int k0  = blockIdx.y * 128;
  for (int i = tid; i < B_ * 128; i += 256) {
    const int b = i >> 7, k = i & 127;
    se[b][k] = siluf(emb[b * TED_ + k0 + k]);
  }
  __syncthreads();
  float a0 = 0.f, a1 = 0.f, a2 = 0.f, a3 = 0.f;
  const float* Wp = emb_W + (size_t)k0 * TWO_D_ + j;
  for (int k = 0; k < 128; ++k) {
    const float w = Wp[(size_t)k * TWO_D_];
    a0 += se[0][k] * w; a1 += se[1][k] * w;
    a2 += se[2][k] * w; a3 += se[3][k] * w;
  }
  if (blockIdx.y == 0) {
    const float bb = emb_b[j];
    a0 += bb; a1 += bb; a2 += bb; a3 += bb;
  }
  atomicAdd(&emb_out[0 * TWO_D_ + j], a0);
  atomicAdd(&emb_out[1 * TWO_D_ + j], a1);
  atomicAdd(&emb_out[2 * TWO_D_ + j], a2);
  atomicAdd(&emb_out[3 * TWO_D_ + j], a3);
}

// ---------------------------------------------------------------------------
// kprep: transpose + convert W1/W2 to bf16 images.
//   img1[h][n=512][k=128] = W1[h][k][n]   (B-operand layout for GEMM1)
//   img2[h][n=128][k=512] = W2[h][k][n]   (B-operand layout for GEMM2)
// 64 blocks: t<32 -> W1 tile (h=t>>2, c=t&3), else W2 tile.
// ---------------------------------------------------------------------------
__global__ __launch_bounds__(256) void kprep(
    const float* __restrict__ W1, const float* __restrict__ W2,
    unsigned short* __restrict__ img1, unsigned short* __restrict__ img2) {
  __shared__ float ls[128][129];
  const int t = blockIdx.x;
  const bool isW2 = (t >= 32);
  const int h = (t & 31) >> 2, c = t & 3;
  const int tid = threadIdx.x;
  const float* src;
  int rstride;
  if (!isW2) { src = W1 + (size_t)h * 65536 + c * 128;               rstride = 512; }
  else       { src = W2 + (size_t)h * 65536 + (size_t)c * 128 * 128; rstride = 128; }
  for (int i = tid; i < 128 * 32; i += 256) {
    const int r = i >> 5, c4 = (i & 31) << 2;
    const float4 v = *reinterpret_cast<const float4*>(src + (size_t)r * rstride + c4);
    ls[r][c4] = v.x; ls[r][c4 + 1] = v.y; ls[r][c4 + 2] = v.z; ls[r][c4 + 3] = v.w;
  }
  __syncthreads();
  unsigned short* dst;
  int rowstride;
  if (!isW2) { dst = img1 + (size_t)h * 65536 + (size_t)c * 128 * 128; rowstride = 128; }
  else       { dst = img2 + (size_t)h * 65536 + c * 128;               rowstride = 512; }
  for (int u = tid; u < 2048; u += 256) {
    const int nn = u >> 4, kb = (u & 15) << 3;
    unsigned int p[4];
    #pragma unroll
    for (int q = 0; q < 4; ++q) {
      const unsigned int lo = f2bf(ls[kb + 2 * q][nn]);
      const unsigned int hi = f2bf(ls[kb + 2 * q + 1][nn]);
      p[q] = lo | (hi << 16);
    }
    *reinterpret_cast<uint4*>(dst + (size_t)nn * rowstride + kb) =
        make_uint4(p[0], p[1], p[2], p[3]);
  }
}

// ---------------------------------------------------------------------------
// k1: per-head MLP via bf16 MFMA (16x16x32).
// Block: 64 tokens x 1 head, 4 waves (256 thr).
// GEMM1 (64x512, K=128) chunked in 4 x 128 FFN-cols; wave w owns n-local
// [w*32, w*32+32). GELU -> h1 chunk in LDS (bf16, XOR-swizzled). GEMM2
// (64x128, K=512) accumulates over chunks; wave w owns d in [w*32, w*32+32).
// Weights come as pre-transposed bf16 images read directly from global as
// MFMA B-fragments (16B/lane, coalesced). Only h1 round-trips LDS.
// ---------------------------------------------------------------------------
__global__ __launch_bounds__(256) void k1_mfma(
    const float* __restrict__ x,
    const unsigned short* __restrict__ img1,
    const unsigned short* __restrict__ img2,
    const float* __restrict__ b1, const float* __restrict__ b2,
    float* __restrict__ y) {
  __shared__ unsigned short h1s[64 * 128];  // XOR-swizzled [m][k-local]
  const int h = blockIdx.y, m0 = blockIdx.x * 64;
  const int tid = threadIdx.x, w = tid >> 6, l = tid & 63;
  const int lr = l & 15, lg = l >> 4;

  // Preload x A-fragments: xf[mf][kk]; lane l holds A[m=lr][k=kk*32+lg*8+j].
  bf16x8 xf[4][4];
  {
    const float* xp = x + (size_t)m0 * D_ + h * LD_;
    #pragma unroll
    for (int mf = 0; mf < 4; ++mf) {
      const float* rp = xp + (size_t)(mf * 16 + lr) * D_ + lg * 8;
      #pragma unroll
      for (int kk = 0; kk < 4; ++kk) {
        const float4 a = *reinterpret_cast<const float4*>(rp + kk * 32);
        const float4 b = *reinterpret_cast<const float4*>(rp + kk * 32 + 4);
        bf16x8 f;
        f[0] = (short)f2bf(a.x); f[1] = (short)f2bf(a.y);
        f[2] = (short)f2bf(a.z); f[3] = (short)f2bf(a.w);
        f[4] = (short)f2bf(b.x); f[5] = (short)f2bf(b.y);
        f[6] = (short)f2bf(b.z); f[7] = (short)f2bf(b.w);
        xf[mf][kk] = f;
      }
    }
  }

  const unsigned short* w1b = img1 + (size_t)h * 65536;  // [n=512][k=128]
  const unsigned short* w2b = img2 + (size_t)h * 65536;  // [n=128][k=512]

  f32x4 acc2[4][2];
  #pragma unroll
  for (int mf = 0; mf < 4; ++mf)
    #pragma unroll
    for (int nf = 0; nf < 2; ++nf)
      acc2[mf][nf] = (f32x4){0.f, 0.f, 0.f, 0.f};

  for (int c = 0; c < 4; ++c) {
    // ---- GEMM1: h1_chunk = x @ W1[:, c*128 : +128]
    f32x4 acc1[4][2];
    #pragma unroll
    for (int mf = 0; mf < 4; ++mf)
      #pragma unroll
      for (int nf = 0; nf < 2; ++nf)
        acc1[mf][nf] = (f32x4){0.f, 0.f, 0.f, 0.f};
    #pragma unroll
    for (int kk = 0; kk < 4; ++kk) {
      const int ko = kk * 32 + lg * 8;
      const bf16x8 bA = *reinterpret_cast<const bf16x8*>(
          w1b + (size_t)(c * 128 + w * 32 + lr) * 128 + ko);
      const bf16x8 bB = *reinterpret_cast<const bf16x8*>(
          w1b + (size_t)(c * 128 + w * 32 + 16 + lr) * 128 + ko);
      #pragma unroll
      for (int mf = 0; mf < 4; ++mf) {
        acc1[mf][0] = __builtin_amdgcn_mfma_f32_16x16x32_bf16(xf[mf][kk], bA, acc1[mf][0], 0, 0, 0);
        acc1[mf][1] = __builtin_amdgcn_mfma_f32_16x16x32_bf16(xf[mf][kk], bB, acc1[mf][1], 0, 0, 0);
      }
    }
    __syncthreads();  // previous chunk's h1s fully consumed
    // ---- bias + GELU -> h1s (bf16, swizzled). C-frag: row=lg*4+r, col=lr.
    const float bv0 = b1[h * FFN_ + c * 128 + w * 32 + lr];
    const float bv1 = b1[h * FFN_ + c * 128 + w * 32 + 16 + lr];
    #pragma unroll
    for (int mf = 0; mf < 4; ++mf) {
      #pragma unroll
      for (int r = 0; r < 4; ++r) {
        const int m = mf * 16 + lg * 4 + r;
        const int sw = (m & 7) << 4;
        {
          const int kcol = w * 32 + lr;
          *(unsigned short*)((char*)h1s + ((m * 256 + kcol * 2) ^ sw)) =
              f2bf(geluf(acc1[mf][0][r] + bv0));
        }
        {
          const int kcol = w * 32 + 16 + lr;
          *(unsigned short*)((char*)h1s + ((m * 256 + kcol * 2) ^ sw)) =
              f2bf(geluf(acc1[mf][1][r] + bv1));
        }
      }
    }
    __syncthreads();  // h1s chunk ready
    // ---- GEMM2: acc2 += h1_chunk @ W2[c*128 : +128, :]
    #pragma unroll
    for (int kk = 0; kk < 4; ++kk) {
      const int ko = kk * 32 + lg * 8;
      bf16x8 af[4];
      #pragma unroll
      for (int mf = 0; mf < 4; ++mf) {
        const int m = mf * 16 + lr;
        af[mf] = *reinterpret_cast<const bf16x8*>(
            (char*)h1s + ((m * 256 + ko * 2) ^ ((m & 7) << 4)));
      }
      const bf16x8 bA = *reinterpret_cast<const bf16x8*>(
          w2b + (size_t)(w * 32 + lr) * 512 + c * 128 + ko);
      const bf16x8 bB = *reinterpret_cast<const bf16x8*>(
          w2b + (size_t)(w * 32 + 16 + lr) * 512 + c * 128 + ko);
      #pragma unroll
      for (int mf = 0; mf < 4; ++mf) {
        acc2[mf][0] = __builtin_amdgcn_mfma_f32_16x16x32_bf16(af[mf], bA, acc2[mf][0], 0, 0, 0);
        acc2[mf][1] = __builtin_amdgcn_mfma_f32_16x16x32_bf16(af[mf], bB, acc2[mf][1], 0, 0, 0);
      }
    }
  }

  // ---- epilogue: y = acc2 + b2
  #pragma unroll
  for (int mf = 0; mf < 4; ++mf) {
    #pragma unroll
    for (int nf = 0; nf < 2; ++nf) {
      const int d = w * 32 + nf * 16 + lr;
      const float bb = b2[h * LD_ + d];
      #pragma unroll
      for (int r = 0; r < 4; ++r) {
        const int m = m0 + mf * 16 + lg * 4 + r;
        y[(size_t)m * D_ + h * LD_ + d] = acc2[mf][nf][r] + bb;
      }
    }
  }
}

// ---------------------------------------------------------------------------
// k2: LayerNorm + (1+scale)/shift modulate + SiLU, in place on y.
// ---------------------------------------------------------------------------
__global__ __launch_bounds__(256) void k2_ln(
    float* __restrict__ y, const float* __restrict__ ln_w,
    const float* __restrict__ ln_b, const float* __restrict__ emb_out) {
  __shared__ float red[8];
  const int bt  = blockIdx.x;
  const int b   = bt >> 12;
  const int tid = threadIdx.x;
  const int d   = tid * 4;
  float4 v = *reinterpret_cast<const float4*>(y + (size_t)bt * D_ + d);
  float s  = v.x + v.y + v.z + v.w;
  float s2 = v.x*v.x + v.y*v.y + v.z*v.z + v.w*v.w;
  #pragma unroll
  for (int off = 32; off > 0; off >>= 1) {
    s  += __shfl_down(s, off);
    s2 += __shfl_down(s2, off);
  }
  if ((tid & 63) == 0) { red[tid >> 6] = s; red[4 + (tid >> 6)] = s2; }
  __syncthreads();
  const float S  = red[0] + red[1] + red[2] + red[3];
  const float S2 = red[4] + red[5] + red[6] + red[7];
  const float mu   = S * (1.0f / D_);
  const float rstd = rsqrtf(S2 * (1.0f / D_) - mu * mu + LN_EPS_);
  const float4 lw = *reinterpret_cast<const float4*>(ln_w + d);
  const float4 lb = *reinterpret_cast<const float4*>(ln_b + d);
  const float4 sc = *reinterpret_cast<const float4*>(emb_out + (size_t)b * TWO_D_ + d);
  const float4 sh = *reinterpret_cast<const float4*>(emb_out + (size_t)b * TWO_D_ + D_ + d);
  v.x = siluf(((v.x - mu) * rstd * lw.x + lb.x) * (1.0f + sc.x) + sh.x);
  v.y = siluf(((v.y - mu) * rstd * lw.y + lb.y) * (1.0f + sc.y) + sh.y);
  v.z = siluf(((v.z - mu) * rstd * lw.z + lb.z) * (1.0f + sc.z) + sh.z);
  v.w = siluf(((v.w - mu) * rstd * lw.w + lb.w) * (1.0f + sc.w) + sh.w);
  *reinterpret_cast<float4*>(y + (size_t)bt * D_ + d) = v;
}

// ---------------------------------------------------------------------------
// k3: out = x + (h @ out_W + out_b). fp32 VALU (MFMA port next round).
// ---------------------------------------------------------------------------
__global__ __launch_bounds__(256) void k3_out(
    const float* __restrict__ hbuf, const float* __restrict__ out_W,
    const float* __restrict__ out_b, const float* __restrict__ x,
    float* __restrict__ out) {
  __shared__ float hs[64][129];
  const int m0  = blockIdx.x * 64;
  const int n0  = blockIdx.y * 128;
  const int tid = threadIdx.x;
  const int tn  = tid & 31;
  const int tm  = tid >> 5;
  float acc[8][4];
  #pragma unroll
  for (int i = 0; i < 8; ++i)
    #pragma unroll
    for (int q = 0; q < 4; ++q) acc[i][q] = 0.f;
  for (int kc = 0; kc < 8; ++kc) {
    for (int i = tid; i < 64 * 32; i += 256) {
      const int m = i >> 5, c = (i & 31) * 4;
      const float4 v = *reinterpret_cast<const float4*>(
          hbuf + (size_t)(m0 + m) * D_ + kc * 128 + c);
      hs[m][c] = v.x; hs[m][c+1] = v.y; hs[m][c+2] = v.z; hs[m][c+3] = v.w;
    }
    __syncthreads();
    const float* Wp = out_W + (size_t)(kc * 128) * D_ + n0 + tn * 4;
    for (int k = 0; k < 128; ++k) {
      const float4 w = *reinterpret_cast<const float4*>(Wp + (size_t)k * D_);
      #pragma unroll
      for (int i = 0; i < 8; ++i) {
        const float hv = hs[tm * 8 + i][k];
        acc[i][0] += hv * w.x; acc[i][1] += hv * w.y;
        acc[i][2] += hv * w.z; acc[i][3] += hv * w.w;
      }
    }
    __syncthreads();
  }
  const int n = n0 + tn * 4;
  const float4 bv = *reinterpret_cast<const float4*>(out_b + n);
  #pragma unroll
  for (int i = 0; i < 8; ++i) {
    const int m = m0 + tm * 8 + i;
    const float4 xv = *reinterpret_cast<const float4*>(x + (size_t)m * D_ + n);
    float4 o;
    o.x = acc[i][0] + bv.x + xv.x;
    o.y = acc[i][1] + bv.y + xv.y;
    o.z = acc[i][2] + bv.z + xv.z;
    o.w = acc[i][3] + bv.w + xv.w;
    *reinterpret_cast<float4*>(out + (size_t)m * D_ + n) = o;
  }
}

// ---------------------------------------------------------------------------
extern "C" void kernel_launch(void* const* d_in, const int* in_sizes, int n_in,
                              void* d_out, int out_size, void* d_ws, size_t ws_size,
                              hipStream_t stream) {
  const float* x     = (const float*)d_in[0];
  const float* emb   = (const float*)d_in[1];
  const float* W1    = (const float*)d_in[2];
  const float* b1    = (const float*)d_in[3];
  const float* W2    = (const float*)d_in[4];
  const float* b2    = (const float*)d_in[5];
  const float* ln_w  = (const float*)d_in[6];
  const float* ln_b  = (const float*)d_in[7];
  const float* emb_W = (const float*)d_in[8];
  const float* emb_b = (const float*)d_in[9];
  const float* out_W = (const float*)d_in[10];
  const float* out_b = (const float*)d_in[11];
  float* out = (float*)d_out;

  float*          emb_out = (float*)((char*)d_ws + WS_EMB_OFF);
  unsigned short* img1    = (unsigned short*)((char*)d_ws + WS_IMG1_OFF);
  unsigned short* img2    = (unsigned short*)((char*)d_ws + WS_IMG2_OFF);
  float*          ybuf    = (float*)((char*)d_ws + WS_Y_OFF);

  hipMemsetAsync(emb_out, 0, B_ * TWO_D_ * sizeof(float), stream);
  k0_emb<<<dim3(TWO_D_ / 256, 16), 256, 0, stream>>>(emb, emb_W, emb_b, emb_out);
  kprep<<<64, 256, 0, stream>>>(W1, W2, img1, img2);
  k1_mfma<<<dim3(NTOK_ / 64, H_), 256, 0, stream>>>(x, img1, img2, b1, b2, ybuf);
  k2_ln<<<NTOK_, 256, 0, stream>>>(ybuf, ln_w, ln_b, emb_out);
  k3_out<<<dim3(NTOK_ / 64, D_ / 128), 256, 0, stream>>>(ybuf, out_W, out_b, x, out);
}

// Round 3
// 299.377 us; speedup vs baseline: 4.1614x; 2.1087x over previous
//
#include <hip/hip_runtime.h>
#include <hip/hip_bf16.h>
#include <math.h>

// Problem constants
#define B_     4
#define T_     4096
#define H_     8
#define LD_    128
#define FFN_   512
#define D_     1024
#define TED_   2048
#define TWO_D_ 2048
#define NTOK_  (B_ * T_)      // 16384
#define LN_EPS_ 1e-5f

// ws layout (bytes)
#define WS_EMB_OFF   0                     // 32 KB   (B x 2D fp32)
#define WS_IMG1_OFF  (64 * 1024)           // 1 MB    bf16 [h][n=512][k=128]
#define WS_IMG2_OFF  ((64 << 10) + (1 << 20))  // 1 MB bf16 [h][n=128][k=512]
#define WS_IMGO_OFF  ((64 << 10) + (2 << 20))  // 2 MB bf16 [n=1024][k=1024]
#define WS_Y_OFF     (8 << 20)             // 32 MB bf16 y (in-place -> h)

typedef short bf16x8 __attribute__((ext_vector_type(8)));
typedef float f32x4  __attribute__((ext_vector_type(4)));

__device__ __forceinline__ float siluf(float v) { return v / (1.0f + expf(-v)); }
__device__ __forceinline__ float geluf(float v) {
  return 0.5f * v * (1.0f + erff(v * 0.70710678118654752440f));
}
__device__ __forceinline__ unsigned short f2bf(float v) {  // RNE float->bf16 bits
  unsigned int u = __float_as_uint(v);
  u += 0x7fffu + ((u >> 16) & 1u);
  return (unsigned short)(u >> 16);
}
__device__ __forceinline__ unsigned int pack2(float a, float b) {
  return (unsigned int)f2bf(a) | ((unsigned int)f2bf(b) << 16);
}
__device__ __forceinline__ void unpack8(uint4 u, float* v) {
  v[0] = __uint_as_float(u.x << 16); v[1] = __uint_as_float(u.x & 0xffff0000u);
  v[2] = __uint_as_float(u.y << 16); v[3] = __uint_as_float(u.y & 0xffff0000u);
  v[4] = __uint_as_float(u.z << 16); v[5] = __uint_as_float(u.z & 0xffff0000u);
  v[6] = __uint_as_float(u.w << 16); v[7] = __uint_as_float(u.w & 0xffff0000u);
}

// ---------------------------------------------------------------------------
// k0: emb_out[b][j] = silu(emb[b]) @ emb_W[:, j] + emb_b[j]
// ---------------------------------------------------------------------------
__global__ __launch_bounds__(256) void k0_emb(
    const float* __restrict__ emb, const float* __restrict__ emb_W,
    const float* __restrict__ emb_b, float* __restrict__ emb_out) {
  __shared__ float se[B_][128];
  const int tid = threadIdx.x;
  const int j   = blockIdx.x * 256 + tid;
  const int k0  = blockIdx.y * 128;
  for (int i = tid; i < B_ * 128; i += 256) {
    const int b = i >> 7, k = i & 127;
    se[b][k] = siluf(emb[b * TED_ + k0 + k]);
  }
  __syncthreads();
  float a0 = 0.f, a1 = 0.f, a2 = 0.f, a3 = 0.f;
  const float* Wp = emb_W + (size_t)k0 * TWO_D_ + j;
  for (int k = 0; k < 128; ++k) {
    const float w = Wp[(size_t)k * TWO_D_];
    a0 += se[0][k] * w; a1 += se[1][k] * w;
    a2 += se[2][k] * w; a3 += se[3][k] * w;
  }
  if (blockIdx.y == 0) {
    const float bb = emb_b[j];
    a0 += bb; a1 += bb; a2 += bb; a3 += bb;
  }
  atomicAdd(&emb_out[0 * TWO_D_ + j], a0);
  atomicAdd(&emb_out[1 * TWO_D_ + j], a1);
  atomicAdd(&emb_out[2 * TWO_D_ + j], a2);
  atomicAdd(&emb_out[3 * TWO_D_ + j], a3);
}

// ---------------------------------------------------------------------------
// kprep: transpose + convert weights to bf16 images (B-operand layout).
//   t <  32 : img1[h][n=512][k=128] = W1[h][k][n]
//   t <  64 : img2[h][n=128][k=512] = W2[h][f][d]
//   t >= 64 : imgO[n=1024][k=1024]  = out_W[k][n]   (64 tiles of 128x128)
// ---------------------------------------------------------------------------
__global__ __launch_bounds__(256) void kprep(
    const float* __restrict__ W1, const float* __restrict__ W2,
    const float* __restrict__ out_W,
    unsigned short* __restrict__ img1, unsigned short* __restrict__ img2,
    unsigned short* __restrict__ imgO) {
  __shared__ float ls[128][129];
  const int t = blockIdx.x;
  const int tid = threadIdx.x;
  const float* src;
  unsigned short* dst;
  int rstride, dstride;
  if (t < 32) {
    const int h = t >> 2, c = t & 3;
    src = W1 + (size_t)h * 65536 + c * 128;               rstride = 512;
    dst = img1 + (size_t)h * 65536 + (size_t)c * 128 * 128; dstride = 128;
  } else if (t < 64) {
    const int h = (t - 32) >> 2, c = t & 3;
    src = W2 + (size_t)h * 65536 + (size_t)c * 128 * 128; rstride = 128;
    dst = img2 + (size_t)h * 65536 + c * 128;             dstride = 512;
  } else {
    const int tt = t - 64, tr = tt >> 3, tc = tt & 7;
    src = out_W + (size_t)tr * 128 * 1024 + tc * 128;     rstride = 1024;
    dst = imgO + (size_t)tc * 128 * 1024 + tr * 128;      dstride = 1024;
  }
  for (int i = tid; i < 128 * 32; i += 256) {
    const int r = i >> 5, c4 = (i & 31) << 2;
    const float4 v = *reinterpret_cast<const float4*>(src + (size_t)r * rstride + c4);
    ls[r][c4] = v.x; ls[r][c4 + 1] = v.y; ls[r][c4 + 2] = v.z; ls[r][c4 + 3] = v.w;
  }
  __syncthreads();
  for (int u = tid; u < 2048; u += 256) {
    const int nn = u >> 4, kb = (u & 15) << 3;
    unsigned int p[4];
    #pragma unroll
    for (int q = 0; q < 4; ++q)
      p[q] = pack2(ls[kb + 2 * q][nn], ls[kb + 2 * q + 1][nn]);
    *reinterpret_cast<uint4*>(dst + (size_t)nn * dstride + kb) =
        make_uint4(p[0], p[1], p[2], p[3]);
  }
}

// ---------------------------------------------------------------------------
// k1: per-head MLP via bf16 MFMA (16x16x32). Output y stored as bf16.
// ---------------------------------------------------------------------------
__global__ __launch_bounds__(256) void k1_mfma(
    const float* __restrict__ x,
    const unsigned short* __restrict__ img1,
    const unsigned short* __restrict__ img2,
    const float* __restrict__ b1, const float* __restrict__ b2,
    unsigned short* __restrict__ y) {
  __shared__ unsigned short h1s[64 * 128];  // XOR-swizzled [m][k-local]
  const int h = blockIdx.y, m0 = blockIdx.x * 64;
  const int tid = threadIdx.x, w = tid >> 6, l = tid & 63;
  const int lr = l & 15, lg = l >> 4;

  // Preload x A-fragments: lane l holds A[m=lr][k=kk*32+lg*8+j].
  bf16x8 xf[4][4];
  {
    const float* xp = x + (size_t)m0 * D_ + h * LD_;
    #pragma unroll
    for (int mf = 0; mf < 4; ++mf) {
      const float* rp = xp + (size_t)(mf * 16 + lr) * D_ + lg * 8;
      #pragma unroll
      for (int kk = 0; kk < 4; ++kk) {
        const float4 a = *reinterpret_cast<const float4*>(rp + kk * 32);
        const float4 b = *reinterpret_cast<const float4*>(rp + kk * 32 + 4);
        bf16x8 f;
        f[0] = (short)f2bf(a.x); f[1] = (short)f2bf(a.y);
        f[2] = (short)f2bf(a.z); f[3] = (short)f2bf(a.w);
        f[4] = (short)f2bf(b.x); f[5] = (short)f2bf(b.y);
        f[6] = (short)f2bf(b.z); f[7] = (short)f2bf(b.w);
        xf[mf][kk] = f;
      }
    }
  }

  const unsigned short* w1b = img1 + (size_t)h * 65536;  // [n=512][k=128]
  const unsigned short* w2b = img2 + (size_t)h * 65536;  // [n=128][k=512]

  f32x4 acc2[4][2];
  #pragma unroll
  for (int mf = 0; mf < 4; ++mf)
    #pragma unroll
    for (int nf = 0; nf < 2; ++nf)
      acc2[mf][nf] = (f32x4){0.f, 0.f, 0.f, 0.f};

  for (int c = 0; c < 4; ++c) {
    f32x4 acc1[4][2];
    #pragma unroll
    for (int mf = 0; mf < 4; ++mf)
      #pragma unroll
      for (int nf = 0; nf < 2; ++nf)
        acc1[mf][nf] = (f32x4){0.f, 0.f, 0.f, 0.f};
    #pragma unroll
    for (int kk = 0; kk < 4; ++kk) {
      const int ko = kk * 32 + lg * 8;
      const bf16x8 bA = *reinterpret_cast<const bf16x8*>(
          w1b + (size_t)(c * 128 + w * 32 + lr) * 128 + ko);
      const bf16x8 bB = *reinterpret_cast<const bf16x8*>(
          w1b + (size_t)(c * 128 + w * 32 + 16 + lr) * 128 + ko);
      #pragma unroll
      for (int mf = 0; mf < 4; ++mf) {
        acc1[mf][0] = __builtin_amdgcn_mfma_f32_16x16x32_bf16(xf[mf][kk], bA, acc1[mf][0], 0, 0, 0);
        acc1[mf][1] = __builtin_amdgcn_mfma_f32_16x16x32_bf16(xf[mf][kk], bB, acc1[mf][1], 0, 0, 0);
      }
    }
    __syncthreads();
    const float bv0 = b1[h * FFN_ + c * 128 + w * 32 + lr];
    const float bv1 = b1[h * FFN_ + c * 128 + w * 32 + 16 + lr];
    #pragma unroll
    for (int mf = 0; mf < 4; ++mf) {
      #pragma unroll
      for (int r = 0; r < 4; ++r) {
        const int m = mf * 16 + lg * 4 + r;
        const int sw = (m & 7) << 4;
        {
          const int kcol = w * 32 + lr;
          *(unsigned short*)((char*)h1s + ((m * 256 + kcol * 2) ^ sw)) =
              f2bf(geluf(acc1[mf][0][r] + bv0));
        }
        {
          const int kcol = w * 32 + 16 + lr;
          *(unsigned short*)((char*)h1s + ((m * 256 + kcol * 2) ^ sw)) =
              f2bf(geluf(acc1[mf][1][r] + bv1));
        }
      }
    }
    __syncthreads();
    #pragma unroll
    for (int kk = 0; kk < 4; ++kk) {
      const int ko = kk * 32 + lg * 8;
      bf16x8 af[4];
      #pragma unroll
      for (int mf = 0; mf < 4; ++mf) {
        const int m = mf * 16 + lr;
        af[mf] = *reinterpret_cast<const bf16x8*>(
            (char*)h1s + ((m * 256 + ko * 2) ^ ((m & 7) << 4)));
      }
      const bf16x8 bA = *reinterpret_cast<const bf16x8*>(
          w2b + (size_t)(w * 32 + lr) * 512 + c * 128 + ko);
      const bf16x8 bB = *reinterpret_cast<const bf16x8*>(
          w2b + (size_t)(w * 32 + 16 + lr) * 512 + c * 128 + ko);
      #pragma unroll
      for (int mf = 0; mf < 4; ++mf) {
        acc2[mf][0] = __builtin_amdgcn_mfma_f32_16x16x32_bf16(af[mf], bA, acc2[mf][0], 0, 0, 0);
        acc2[mf][1] = __builtin_amdgcn_mfma_f32_16x16x32_bf16(af[mf], bB, acc2[mf][1], 0, 0, 0);
      }
    }
  }

  // epilogue: y = bf16(acc2 + b2)
  #pragma unroll
  for (int mf = 0; mf < 4; ++mf) {
    #pragma unroll
    for (int nf = 0; nf < 2; ++nf) {
      const int d = w * 32 + nf * 16 + lr;
      const float bb = b2[h * LD_ + d];
      #pragma unroll
      for (int r = 0; r < 4; ++r) {
        const int m = m0 + mf * 16 + lg * 4 + r;
        y[(size_t)m * D_ + h * LD_ + d] = f2bf(acc2[mf][nf][r] + bb);
      }
    }
  }
}

// ---------------------------------------------------------------------------
// k2: LN + modulate + SiLU. One wave per token; in-place bf16 -> bf16.
// grid 4096 blocks x 256 thr (4 waves = 4 tokens).
// ---------------------------------------------------------------------------
__global__ __launch_bounds__(256) void k2_ln(
    unsigned short* __restrict__ y, const float* __restrict__ ln_w,
    const float* __restrict__ ln_b, const float* __restrict__ emb_out) {
  const int tid = threadIdx.x;
  const int bt  = blockIdx.x * 4 + (tid >> 6);
  const int l   = tid & 63;
  const int b   = bt >> 12;
  unsigned short* rowp = y + (size_t)bt * D_ + l * 16;
  const uint4 u0 = *reinterpret_cast<const uint4*>(rowp);
  const uint4 u1 = *reinterpret_cast<const uint4*>(rowp + 8);
  float v[16];
  unpack8(u0, v); unpack8(u1, v + 8);
  float s = 0.f, s2 = 0.f;
  #pragma unroll
  for (int j = 0; j < 16; ++j) { s += v[j]; s2 += v[j] * v[j]; }
  #pragma unroll
  for (int off = 1; off < 64; off <<= 1) {
    s  += __shfl_xor(s, off);
    s2 += __shfl_xor(s2, off);
  }
  const float mu   = s * (1.0f / D_);
  const float rstd = rsqrtf(s2 * (1.0f / D_) - mu * mu + LN_EPS_);
  const int d0 = l * 16;
  float r[16];
  #pragma unroll
  for (int q = 0; q < 4; ++q) {
    const float4 lw = *reinterpret_cast<const float4*>(ln_w + d0 + q * 4);
    const float4 lb = *reinterpret_cast<const float4*>(ln_b + d0 + q * 4);
    const float4 sc = *reinterpret_cast<const float4*>(emb_out + (size_t)b * TWO_D_ + d0 + q * 4);
    const float4 sh = *reinterpret_cast<const float4*>(emb_out + (size_t)b * TWO_D_ + D_ + d0 + q * 4);
    r[q*4+0] = siluf(((v[q*4+0] - mu) * rstd * lw.x + lb.x) * (1.f + sc.x) + sh.x);
    r[q*4+1] = siluf(((v[q*4+1] - mu) * rstd * lw.y + lb.y) * (1.f + sc.y) + sh.y);
    r[q*4+2] = siluf(((v[q*4+2] - mu) * rstd * lw.z + lb.z) * (1.f + sc.z) + sh.z);
    r[q*4+3] = siluf(((v[q*4+3] - mu) * rstd * lw.w + lb.w) * (1.f + sc.w) + sh.w);
  }
  uint4 o0, o1;
  o0.x = pack2(r[0], r[1]);  o0.y = pack2(r[2], r[3]);
  o0.z = pack2(r[4], r[5]);  o0.w = pack2(r[6], r[7]);
  o1.x = pack2(r[8], r[9]);  o1.y = pack2(r[10], r[11]);
  o1.z = pack2(r[12], r[13]); o1.w = pack2(r[14], r[15]);
  *reinterpret_cast<uint4*>(rowp)     = o0;
  *reinterpret_cast<uint4*>(rowp + 8) = o1;
}

// ---------------------------------------------------------------------------
// k3: out = x + (h @ out_W + out_b) via bf16 MFMA. No LDS.
// grid (16384/64=256, 1024/256=4), block 256 (4 waves).
// Wave w owns 64 rows x 64 cols: acc[4 mf][4 nf]. K=1024 in 32 steps.
// A-frags direct from bf16 h; B-frags direct from L2-resident imgO.
// ---------------------------------------------------------------------------
__global__ __launch_bounds__(256) void k3_mfma(
    const unsigned short* __restrict__ hb,
    const unsigned short* __restrict__ imgO,
    const float* __restrict__ out_b, const float* __restrict__ x,
    float* __restrict__ out) {
  const int m0 = blockIdx.x * 64;
  const int n0 = blockIdx.y * 256;
  const int tid = threadIdx.x, w = tid >> 6, l = tid & 63;
  const int lr = l & 15, lg = l >> 4;
  const int nw = n0 + w * 64;

  f32x4 acc[4][4];
  #pragma unroll
  for (int mf = 0; mf < 4; ++mf)
    #pragma unroll
    for (int nf = 0; nf < 4; ++nf)
      acc[mf][nf] = (f32x4){0.f, 0.f, 0.f, 0.f};

  const unsigned short* ap = hb + (size_t)m0 * D_;
  for (int kk = 0; kk < 32; ++kk) {
    const int ko = kk * 32 + lg * 8;
    bf16x8 bfr[4];
    #pragma unroll
    for (int nf = 0; nf < 4; ++nf)
      bfr[nf] = *reinterpret_cast<const bf16x8*>(
          imgO + (size_t)(nw + nf * 16 + lr) * D_ + ko);
    #pragma unroll
    for (int mf = 0; mf < 4; ++mf) {
      const bf16x8 a = *reinterpret_cast<const bf16x8*>(
          ap + (size_t)(mf * 16 + lr) * D_ + ko);
      #pragma unroll
      for (int nf = 0; nf < 4; ++nf)
        acc[mf][nf] = __builtin_amdgcn_mfma_f32_16x16x32_bf16(a, bfr[nf], acc[mf][nf], 0, 0, 0);
    }
  }

  #pragma unroll
  for (int mf = 0; mf < 4; ++mf) {
    #pragma unroll
    for (int nf = 0; nf < 4; ++nf) {
      const int d = nw + nf * 16 + lr;
      const float bb = out_b[d];
      #pragma unroll
      for (int r = 0; r < 4; ++r) {
        const int m = m0 + mf * 16 + lg * 4 + r;
        out[(size_t)m * D_ + d] = acc[mf][nf][r] + bb + x[(size_t)m * D_ + d];
      }
    }
  }
}

// ---------------------------------------------------------------------------
extern "C" void kernel_launch(void* const* d_in, const int* in_sizes, int n_in,
                              void* d_out, int out_size, void* d_ws, size_t ws_size,
                              hipStream_t stream) {
  const float* x     = (const float*)d_in[0];
  const float* emb   = (const float*)d_in[1];
  const float* W1    = (const float*)d_in[2];
  const float* b1    = (const float*)d_in[3];
  const float* W2    = (const float*)d_in[4];
  const float* b2    = (const float*)d_in[5];
  const float* ln_w  = (const float*)d_in[6];
  const float* ln_b  = (const float*)d_in[7];
  const float* emb_W = (const float*)d_in[8];
  const float* emb_b = (const float*)d_in[9];
  const float* out_W = (const float*)d_in[10];
  const float* out_b = (const float*)d_in[11];
  float* out = (float*)d_out;

  float*          emb_out = (float*)((char*)d_ws + WS_EMB_OFF);
  unsigned short* img1    = (unsigned short*)((char*)d_ws + WS_IMG1_OFF);
  unsigned short* img2    = (unsigned short*)((char*)d_ws + WS_IMG2_OFF);
  unsigned short* imgO    = (unsigned short*)((char*)d_ws + WS_IMGO_OFF);
  unsigned short* ybuf    = (unsigned short*)((char*)d_ws + WS_Y_OFF);

  hipMemsetAsync(emb_out, 0, B_ * TWO_D_ * sizeof(float), stream);
  k0_emb<<<dim3(TWO_D_ / 256, 16), 256, 0, stream>>>(emb, emb_W, emb_b, emb_out);
  kprep<<<128, 256, 0, stream>>>(W1, W2, out_W, img1, img2, imgO);
  k1_mfma<<<dim3(NTOK_ / 64, H_), 256, 0, stream>>>(x, img1, img2, b1, b2, ybuf);
  k2_ln<<<NTOK_ / 4, 256, 0, stream>>>(ybuf, ln_w, ln_b, emb_out);
  k3_mfma<<<dim3(NTOK_ / 64, D_ / 256), 256, 0, stream>>>(ybuf, imgO, out_b, x, out);
}

// Round 4
// 257.293 us; speedup vs baseline: 4.8421x; 1.1636x over previous
//
#include <hip/hip_runtime.h>
#include <hip/hip_bf16.h>
#include <math.h>

// Problem constants
#define B_     4
#define T_     4096
#define H_     8
#define LD_    128
#define FFN_   512
#define D_     1024
#define TED_   2048
#define TWO_D_ 2048
#define NTOK_  (B_ * T_)      // 16384
#define LN_EPS_ 1e-5f

// ws layout (bytes)
#define WS_EMB_OFF   0                         // 32 KB   (B x 2D fp32)
#define WS_IMG1_OFF  (64 * 1024)               // 1 MB  bf16 [h][f=512][k=128]
#define WS_IMG2_OFF  ((64 << 10) + (1 << 20))  // 1 MB  bf16 [h][d=128][f=512]
#define WS_IMGO_OFF  ((64 << 10) + (2 << 20))  // 2 MB  bf16 [n=1024][k=1024]
#define WS_Y_OFF     (8 << 20)                 // 32 MB bf16 y (in-place -> h)

typedef short bf16x8 __attribute__((ext_vector_type(8)));
typedef float f32x4  __attribute__((ext_vector_type(4)));
typedef float f32x16 __attribute__((ext_vector_type(16)));
typedef unsigned int u32x4 __attribute__((ext_vector_type(4)));

__device__ __forceinline__ float siluf(float v) { return v / (1.0f + expf(-v)); }
__device__ __forceinline__ float geluf(float v) {
  return 0.5f * v * (1.0f + erff(v * 0.70710678118654752440f));
}
__device__ __forceinline__ unsigned short f2bf(float v) {  // RNE float->bf16 bits
  unsigned int u = __float_as_uint(v);
  u += 0x7fffu + ((u >> 16) & 1u);
  return (unsigned short)(u >> 16);
}
__device__ __forceinline__ unsigned int pack2(float a, float b) {
  return (unsigned int)f2bf(a) | ((unsigned int)f2bf(b) << 16);
}
__device__ __forceinline__ void unpack8(uint4 u, float* v) {
  v[0] = __uint_as_float(u.x << 16); v[1] = __uint_as_float(u.x & 0xffff0000u);
  v[2] = __uint_as_float(u.y << 16); v[3] = __uint_as_float(u.y & 0xffff0000u);
  v[4] = __uint_as_float(u.z << 16); v[5] = __uint_as_float(u.z & 0xffff0000u);
  v[6] = __uint_as_float(u.w << 16); v[7] = __uint_as_float(u.w & 0xffff0000u);
}

// async global->LDS, 16B/lane; LDS dest is wave-uniform base + lane*16.
__device__ __forceinline__ void gload_lds16(const void* g, void* l) {
#pragma clang diagnostic push
#pragma clang diagnostic ignored "-Waddress-space-conversion"
  __builtin_amdgcn_global_load_lds(
      (const __attribute__((address_space(1))) unsigned int*)g,
      (__attribute__((address_space(3))) unsigned int*)l, 16, 0, 0);
#pragma clang diagnostic pop
}

// ---------------------------------------------------------------------------
// k0: emb_out[b][j] = silu(emb[b]) @ emb_W[:, j] + emb_b[j]
// ---------------------------------------------------------------------------
__global__ __launch_bounds__(256) void k0_emb(
    const float* __restrict__ emb, const float* __restrict__ emb_W,
    const float* __restrict__ emb_b, float* __restrict__ emb_out) {
  __shared__ float se[B_][128];
  const int tid = threadIdx.x;
  const int j   = blockIdx.x * 256 + tid;
  const int k0  = blockIdx.y * 128;
  for (int i = tid; i < B_ * 128; i += 256) {
    const int b = i >> 7, k = i & 127;
    se[b][k] = siluf(emb[b * TED_ + k0 + k]);
  }
  __syncthreads();
  float a0 = 0.f, a1 = 0.f, a2 = 0.f, a3 = 0.f;
  const float* Wp = emb_W + (size_t)k0 * TWO_D_ + j;
  for (int k = 0; k < 128; ++k) {
    const float w = Wp[(size_t)k * TWO_D_];
    a0 += se[0][k] * w; a1 += se[1][k] * w;
    a2 += se[2][k] * w; a3 += se[3][k] * w;
  }
  if (blockIdx.y == 0) {
    const float bb = emb_b[j];
    a0 += bb; a1 += bb; a2 += bb; a3 += bb;
  }
  atomicAdd(&emb_out[0 * TWO_D_ + j], a0);
  atomicAdd(&emb_out[1 * TWO_D_ + j], a1);
  atomicAdd(&emb_out[2 * TWO_D_ + j], a2);
  atomicAdd(&emb_out[3 * TWO_D_ + j], a3);
}

// ---------------------------------------------------------------------------
// kprep: transpose + convert weights to bf16 images.
//   t <  32 : img1[h][f=512][k=128] = W1[h][k][f]
//   t <  64 : img2[h][d=128][f=512] = W2[h][f][d]
//   t >= 64 : imgO[n=1024][k=1024]  = out_W[k][n]
// ---------------------------------------------------------------------------
__global__ __launch_bounds__(256) void kprep(
    const float* __restrict__ W1, const float* __restrict__ W2,
    const float* __restrict__ out_W,
    unsigned short* __restrict__ img1, unsigned short* __restrict__ img2,
    unsigned short* __restrict__ imgO) {
  __shared__ float ls[128][129];
  const int t = blockIdx.x;
  const int tid = threadIdx.x;
  const float* src;
  unsigned short* dst;
  int rstride, dstride;
  if (t < 32) {
    const int h = t >> 2, c = t & 3;
    src = W1 + (size_t)h * 65536 + c * 128;               rstride = 512;
    dst = img1 + (size_t)h * 65536 + (size_t)c * 128 * 128; dstride = 128;
  } else if (t < 64) {
    const int h = (t - 32) >> 2, c = t & 3;
    src = W2 + (size_t)h * 65536 + (size_t)c * 128 * 128; rstride = 128;
    dst = img2 + (size_t)h * 65536 + c * 128;             dstride = 512;
  } else {
    const int tt = t - 64, tr = tt >> 3, tc = tt & 7;
    src = out_W + (size_t)tr * 128 * 1024 + tc * 128;     rstride = 1024;
    dst = imgO + (size_t)tc * 128 * 1024 + tr * 128;      dstride = 1024;
  }
  for (int i = tid; i < 128 * 32; i += 256) {
    const int r = i >> 5, c4 = (i & 31) << 2;
    const float4 v = *reinterpret_cast<const float4*>(src + (size_t)r * rstride + c4);
    ls[r][c4] = v.x; ls[r][c4 + 1] = v.y; ls[r][c4 + 2] = v.z; ls[r][c4 + 3] = v.w;
  }
  __syncthreads();
  for (int u = tid; u < 2048; u += 256) {
    const int nn = u >> 4, kb = (u & 15) << 3;
    unsigned int p[4];
    #pragma unroll
    for (int q = 0; q < 4; ++q)
      p[q] = pack2(ls[kb + 2 * q][nn], ls[kb + 2 * q + 1][nn]);
    *reinterpret_cast<uint4*>(dst + (size_t)nn * dstride + kb) =
        make_uint4(p[0], p[1], p[2], p[3]);
  }
}

// ---------------------------------------------------------------------------
// k1: per-head MLP, barrier-free, LDS-free. 1 wave = 32 tokens x 1 head.
// GEMM1 swapped (32x32x16): D = mfma(W1^T-frag, x^T-frag) = h1^T, so lane
// holds token in lane&31 and f in regs -> after GELU + 4 shfl_xor(32)
// exchanges, regs ARE the A-fragments for GEMM2. grid (NTOK/128, H), 4 waves.
// ---------------------------------------------------------------------------
__global__ __launch_bounds__(256) void k1_mfma(
    const float* __restrict__ x,
    const unsigned short* __restrict__ img1,
    const unsigned short* __restrict__ img2,
    const float* __restrict__ b1, const float* __restrict__ b2,
    unsigned short* __restrict__ y) {
  const int h = blockIdx.y;
  const int tid = threadIdx.x, w = tid >> 6, l = tid & 63;
  const int t0 = blockIdx.x * 128 + w * 32;
  const int l31 = l & 31, hi = l >> 5;

  // x^T B-fragments: xf[kb], lane holds x[t0+l31][h*128 + kb*16 + hi*8 + 0..7]
  bf16x8 xf[8];
  {
    const float* xr = x + (size_t)(t0 + l31) * D_ + h * LD_ + hi * 8;
    #pragma unroll
    for (int kb = 0; kb < 8; ++kb) {
      const float4 a = *reinterpret_cast<const float4*>(xr + kb * 16);
      const float4 b = *reinterpret_cast<const float4*>(xr + kb * 16 + 4);
      bf16x8 f;
      f[0] = (short)f2bf(a.x); f[1] = (short)f2bf(a.y);
      f[2] = (short)f2bf(a.z); f[3] = (short)f2bf(a.w);
      f[4] = (short)f2bf(b.x); f[5] = (short)f2bf(b.y);
      f[6] = (short)f2bf(b.z); f[7] = (short)f2bf(b.w);
      xf[kb] = f;
    }
  }

  const unsigned short* w1b = img1 + (size_t)h * 65536;  // [f=512][k=128]
  const unsigned short* w2b = img2 + (size_t)h * 65536;  // [d=128][f=512]

  f32x16 acc2[4];
  #pragma unroll
  for (int nt = 0; nt < 4; ++nt)
    #pragma unroll
    for (int r = 0; r < 16; ++r) acc2[nt][r] = 0.f;

  for (int c = 0; c < 16; ++c) {  // 32-f chunks
    // ---- GEMM1 swapped: acc1 = h1^T tile (f_local x token)
    f32x16 acc1;
    #pragma unroll
    for (int r = 0; r < 16; ++r) acc1[r] = 0.f;
    #pragma unroll
    for (int kb = 0; kb < 8; ++kb) {
      const bf16x8 a = *reinterpret_cast<const bf16x8*>(
          w1b + (size_t)(c * 32 + l31) * 128 + kb * 16 + hi * 8);
      acc1 = __builtin_amdgcn_mfma_f32_32x32x16_bf16(a, xf[kb], acc1, 0, 0, 0);
    }
    // ---- bias + GELU (reg r: f_local = 8*(r>>2) + 4*hi + (r&3))
    float g[16];
    #pragma unroll
    for (int q = 0; q < 4; ++q) {
      const float4 bq = *reinterpret_cast<const float4*>(
          b1 + h * FFN_ + c * 32 + q * 8 + hi * 4);
      g[q*4+0] = geluf(acc1[q*4+0] + bq.x);
      g[q*4+1] = geluf(acc1[q*4+1] + bq.y);
      g[q*4+2] = geluf(acc1[q*4+2] + bq.z);
      g[q*4+3] = geluf(acc1[q*4+3] + bq.w);
    }
    // ---- pack to bf16 pairs: P[q][s] holds f = (8q+4hi+2s, +1)
    unsigned int P[4][2];
    #pragma unroll
    for (int q = 0; q < 4; ++q) {
      P[q][0] = pack2(g[q*4+0], g[q*4+1]);
      P[q][1] = pack2(g[q*4+2], g[q*4+3]);
    }
    // ---- assemble GEMM2 A-frags: lane needs f = kb2*16 + hi*8 + j.
    // Own halves + partner (lane^32) halves via shfl_xor.
    unsigned int A2[2][4];
    #pragma unroll
    for (int half = 0; half < 2; ++half) {
      const int qe = half * 2, qo = half * 2 + 1;
      #pragma unroll
      for (int s = 0; s < 2; ++s) {
        const unsigned int offer = hi ? P[qe][s] : P[qo][s];
        const unsigned int recv =
            (unsigned int)__shfl_xor((int)offer, 32);
        A2[half][s]     = hi ? recv : P[qe][s];
        A2[half][s + 2] = hi ? P[qo][s] : recv;
      }
    }
    // ---- GEMM2: acc2[nt] += h1_chunk @ W2 (K=32 per chunk)
    #pragma unroll
    for (int kb2 = 0; kb2 < 2; ++kb2) {
      u32x4 t;
      t[0] = A2[kb2][0]; t[1] = A2[kb2][1];
      t[2] = A2[kb2][2]; t[3] = A2[kb2][3];
      const bf16x8 a2 = __builtin_bit_cast(bf16x8, t);
      #pragma unroll
      for (int nt = 0; nt < 4; ++nt) {
        const bf16x8 b2f = *reinterpret_cast<const bf16x8*>(
            w2b + (size_t)(nt * 32 + l31) * 512 + c * 32 + kb2 * 16 + hi * 8);
        acc2[nt] = __builtin_amdgcn_mfma_f32_32x32x16_bf16(a2, b2f, acc2[nt], 0, 0, 0);
      }
    }
  }

  // ---- epilogue: y[t][h*128+d] = bf16(acc2 + b2); d = nt*32+l31,
  // t = t0 + (r&3) + 8*(r>>2) + 4*hi
  #pragma unroll
  for (int nt = 0; nt < 4; ++nt) {
    const int d = nt * 32 + l31;
    const float bb = b2[h * LD_ + d];
    #pragma unroll
    for (int r = 0; r < 16; ++r) {
      const int tq = t0 + (r & 3) + 8 * (r >> 2) + 4 * hi;
      y[(size_t)tq * D_ + h * LD_ + d] = f2bf(acc2[nt][r] + bb);
    }
  }
}

// ---------------------------------------------------------------------------
// k2: LN + modulate + SiLU. One wave per token; in-place bf16 -> bf16.
// ---------------------------------------------------------------------------
__global__ __launch_bounds__(256) void k2_ln(
    unsigned short* __restrict__ y, const float* __restrict__ ln_w,
    const float* __restrict__ ln_b, const float* __restrict__ emb_out) {
  const int tid = threadIdx.x;
  const int bt  = blockIdx.x * 4 + (tid >> 6);
  const int l   = tid & 63;
  const int b   = bt >> 12;
  unsigned short* rowp = y + (size_t)bt * D_ + l * 16;
  const uint4 u0 = *reinterpret_cast<const uint4*>(rowp);
  const uint4 u1 = *reinterpret_cast<const uint4*>(rowp + 8);
  float v[16];
  unpack8(u0, v); unpack8(u1, v + 8);
  float s = 0.f, s2 = 0.f;
  #pragma unroll
  for (int j = 0; j < 16; ++j) { s += v[j]; s2 += v[j] * v[j]; }
  #pragma unroll
  for (int off = 1; off < 64; off <<= 1) {
    s  += __shfl_xor(s, off);
    s2 += __shfl_xor(s2, off);
  }
  const float mu   = s * (1.0f / D_);
  const float rstd = rsqrtf(s2 * (1.0f / D_) - mu * mu + LN_EPS_);
  const int d0 = l * 16;
  float r[16];
  #pragma unroll
  for (int q = 0; q < 4; ++q) {
    const float4 lw = *reinterpret_cast<const float4*>(ln_w + d0 + q * 4);
    const float4 lb = *reinterpret_cast<const float4*>(ln_b + d0 + q * 4);
    const float4 sc = *reinterpret_cast<const float4*>(emb_out + (size_t)b * TWO_D_ + d0 + q * 4);
    const float4 sh = *reinterpret_cast<const float4*>(emb_out + (size_t)b * TWO_D_ + D_ + d0 + q * 4);
    r[q*4+0] = siluf(((v[q*4+0] - mu) * rstd * lw.x + lb.x) * (1.f + sc.x) + sh.x);
    r[q*4+1] = siluf(((v[q*4+1] - mu) * rstd * lw.y + lb.y) * (1.f + sc.y) + sh.y);
    r[q*4+2] = siluf(((v[q*4+2] - mu) * rstd * lw.z + lb.z) * (1.f + sc.z) + sh.z);
    r[q*4+3] = siluf(((v[q*4+3] - mu) * rstd * lw.w + lb.w) * (1.f + sc.w) + sh.w);
  }
  uint4 o0, o1;
  o0.x = pack2(r[0], r[1]);  o0.y = pack2(r[2], r[3]);
  o0.z = pack2(r[4], r[5]);  o0.w = pack2(r[6], r[7]);
  o1.x = pack2(r[8], r[9]);  o1.y = pack2(r[10], r[11]);
  o1.z = pack2(r[12], r[13]); o1.w = pack2(r[14], r[15]);
  *reinterpret_cast<uint4*>(rowp)     = o0;
  *reinterpret_cast<uint4*>(rowp + 8) = o1;
}

// ---------------------------------------------------------------------------
// k3: out = x + (h @ out_W + out_b), m97-structure MFMA GEMM.
// 128x128 tile, BK=32, 4 waves (64x64 each), global_load_lds staging,
// XCD-bijective swizzle (nwg=1024, q=128). M=16384 N=1024 K=1024.
// ---------------------------------------------------------------------------
__global__ __launch_bounds__(256) void k3_mfma(
    const unsigned short* __restrict__ hb,
    const unsigned short* __restrict__ imgO,
    const float* __restrict__ out_b, const float* __restrict__ x,
    float* __restrict__ out) {
  __shared__ unsigned short As[128 * 32];  // [m][k] linear, 64B rows
  __shared__ unsigned short Bs[128 * 32];  // [n][k] linear
  const int bid = blockIdx.x;
  const int swz = (bid & 7) * 128 + (bid >> 3);   // XCD-bijective (1024 % 8 == 0)
  const int m0 = (swz >> 3) * 128;
  const int n0 = (swz & 7) * 128;
  const int tid = threadIdx.x, w = tid >> 6, l = tid & 63;
  const int lr = l & 15, lg = l >> 4;
  const int wm0 = (w & 1) * 64, wn0 = (w >> 1) * 64;

  f32x4 acc[4][4];
  #pragma unroll
  for (int mf = 0; mf < 4; ++mf)
    #pragma unroll
    for (int nf = 0; nf < 4; ++nf)
      acc[mf][nf] = (f32x4){0.f, 0.f, 0.f, 0.f};

  const int srow = (l >> 2);          // 0..15 within 16-row chunk
  const int scol = (l & 3) * 8;       // bf16 elems, 16B
  for (int kc = 0; kc < 32; ++kc) {
    // stage A and B tiles: 8 chunks of 16 rows each; wave w does chunks 2w,2w+1
    #pragma unroll
    for (int i = 0; i < 2; ++i) {
      const int c = w * 2 + i;
      const int row = c * 16 + srow;
      gload_lds16(hb   + (size_t)(m0 + row) * D_ + kc * 32 + scol, &As[c * 512]);
      gload_lds16(imgO + (size_t)(n0 + row) * D_ + kc * 32 + scol, &Bs[c * 512]);
    }
    __syncthreads();   // drains vmcnt(0), tiles ready
    bf16x8 af[4], bf[4];
    #pragma unroll
    for (int mf = 0; mf < 4; ++mf)
      af[mf] = *reinterpret_cast<const bf16x8*>(&As[(wm0 + mf * 16 + lr) * 32 + lg * 8]);
    #pragma unroll
    for (int nf = 0; nf < 4; ++nf)
      bf[nf] = *reinterpret_cast<const bf16x8*>(&Bs[(wn0 + nf * 16 + lr) * 32 + lg * 8]);
    #pragma unroll
    for (int mf = 0; mf < 4; ++mf)
      #pragma unroll
      for (int nf = 0; nf < 4; ++nf)
        acc[mf][nf] = __builtin_amdgcn_mfma_f32_16x16x32_bf16(af[mf], bf[nf], acc[mf][nf], 0, 0, 0);
    __syncthreads();   // protect next staging
  }

  #pragma unroll
  for (int mf = 0; mf < 4; ++mf) {
    #pragma unroll
    for (int nf = 0; nf < 4; ++nf) {
      const int n = n0 + wn0 + nf * 16 + lr;
      const float bb = out_b[n];
      #pragma unroll
      for (int r = 0; r < 4; ++r) {
        const int m = m0 + wm0 + mf * 16 + lg * 4 + r;
        out[(size_t)m * D_ + n] = acc[mf][nf][r] + bb + x[(size_t)m * D_ + n];
      }
    }
  }
}

// ---------------------------------------------------------------------------
extern "C" void kernel_launch(void* const* d_in, const int* in_sizes, int n_in,
                              void* d_out, int out_size, void* d_ws, size_t ws_size,
                              hipStream_t stream) {
  const float* x     = (const float*)d_in[0];
  const float* emb   = (const float*)d_in[1];
  const float* W1    = (const float*)d_in[2];
  const float* b1    = (const float*)d_in[3];
  const float* W2    = (const float*)d_in[4];
  const float* b2    = (const float*)d_in[5];
  const float* ln_w  = (const float*)d_in[6];
  const float* ln_b  = (const float*)d_in[7];
  const float* emb_W = (const float*)d_in[8];
  const float* emb_b = (const float*)d_in[9];
  const float* out_W = (const float*)d_in[10];
  const float* out_b = (const float*)d_in[11];
  float* out = (float*)d_out;

  float*          emb_out = (float*)((char*)d_ws + WS_EMB_OFF);
  unsigned short* img1    = (unsigned short*)((char*)d_ws + WS_IMG1_OFF);
  unsigned short* img2    = (unsigned short*)((char*)d_ws + WS_IMG2_OFF);
  unsigned short* imgO    = (unsigned short*)((char*)d_ws + WS_IMGO_OFF);
  unsigned short* ybuf    = (unsigned short*)((char*)d_ws + WS_Y_OFF);

  hipMemsetAsync(emb_out, 0, B_ * TWO_D_ * sizeof(float), stream);
  k0_emb<<<dim3(TWO_D_ / 256, 16), 256, 0, stream>>>(emb, emb_W, emb_b, emb_out);
  kprep<<<128, 256, 0, stream>>>(W1, W2, out_W, img1, img2, imgO);
  k1_mfma<<<dim3(NTOK_ / 128, H_), 256, 0, stream>>>(x, img1, img2, b1, b2, ybuf);
  k2_ln<<<NTOK_ / 4, 256, 0, stream>>>(ybuf, ln_w, ln_b, emb_out);
  k3_mfma<<<1024, 256, 0, stream>>>(ybuf, imgO, out_b, x, out);
}